// Round 5
// baseline (959.182 us; speedup 1.0000x reference)
//
#include <hip/hip_runtime.h>
#include <math.h>

#define TB 256

typedef __attribute__((ext_vector_type(8))) short short8_t;
typedef __attribute__((ext_vector_type(4))) float f32x4;

__device__ __forceinline__ ushort f2bf(float f) {
    uint u = __float_as_uint(f);
    return (ushort)((u + 0x7FFFu + ((u >> 16) & 1u)) >> 16);  // RNE
}

__device__ __forceinline__ void gload_lds16(const void* g, void* l) {
    __builtin_amdgcn_global_load_lds(
        (const __attribute__((address_space(1))) void*)g,
        (__attribute__((address_space(3))) void*)l, 16, 0, 0);
}

// C[M x Nc] = A * B^T, bf16 MFMA 16x16x32, f32 accumulate. 128x128x32 tiles,
// double-buffered LDS, issue-early prefetch. Batched via blockIdx.z with byte
// strides strA/strB/strC.
// CONV 1: A f32 reg-staged+converted. CONV 0: A bf16 via global_load_lds.
// EPI 0: bf16 C = acc + bias[col]      (QKV)
// EPI 1: f32  C = acc * alpha          (S; softmax applies causal mask)
// EPI 2: bf16 C = acc, cols at +off    (PV -> T)
// EPI 3: f32  C = acc + bias[col]      (proj)
// TRI : causal block skip: return if n0 > m0+off+127
// KLIM: kend = min(K, n0+off+BN)       (PV causal k-limit)
// REVX: reverse blockIdx.x mapping (longest-K blocks dispatch first)
template<int CONV, int EPI, bool TRI, bool KLIM, bool REVX>
__global__ __launch_bounds__(TB)
void gemm_bf16(const void* __restrict__ Av, int lda,
               const ushort* __restrict__ Bp, int ldb,
               const float* __restrict__ bias,
               void* __restrict__ Cv, int ldc,
               int K, float alpha, int off,
               size_t strA, size_t strB, size_t strC)
{
    constexpr int BM = 128, BN = 128, BK = 32;
    const int m0 = blockIdx.y * BM;
    const int nb = REVX ? (gridDim.x - 1 - blockIdx.x) : blockIdx.x;
    const int n0 = nb * BN;
    if (TRI && n0 > m0 + off + BM - 1) return;   // fully-masked causal block

    const void*   Az = (const char*)Av + (size_t)blockIdx.z * strA;
    const ushort* B  = (const ushort*)((const char*)Bp + (size_t)blockIdx.z * strB);
    void*         Cz = (char*)Cv + (size_t)blockIdx.z * strC;

    const int tid = threadIdx.x;
    const int lane = tid & 63;
    const int wid = tid >> 6;
    const int wr = wid >> 1, wc = wid & 1;       // wave -> 64x64 quadrant

    __shared__ __align__(16) ushort As[2][BM * BK];
    __shared__ __align__(16) ushort Bs[2][BN * BK];

    f32x4 acc[4][4];
    const f32x4 zero = {0.f, 0.f, 0.f, 0.f};
    #pragma unroll
    for (int mi = 0; mi < 4; mi++)
        #pragma unroll
        for (int ni = 0; ni < 4; ni++) acc[mi][ni] = zero;

    const int klim = KLIM ? (n0 + off + BN) : K;
    const int kend = klim < K ? klim : K;
    const int nt = kend / BK;

    auto STAGE = [&](int t, int bufi) {
        const int k0 = t * BK;
        if (CONV) {
            const float* Af = (const float*)Az;
            #pragma unroll
            for (int h = 0; h < 2; h++) {
                const int q = tid + h * TB;      // 0..511
                const int row = q >> 2;          // 0..127
                const int kp = (q & 3) * 8;      // 0,8,16,24
                const float* src = &Af[(size_t)(m0 + row) * lda + k0 + kp];
                float4 u0 = *(const float4*)src;
                float4 u1 = *(const float4*)(src + 4);
                short8_t s;
                s[0] = (short)f2bf(u0.x); s[1] = (short)f2bf(u0.y);
                s[2] = (short)f2bf(u0.z); s[3] = (short)f2bf(u0.w);
                s[4] = (short)f2bf(u1.x); s[5] = (short)f2bf(u1.y);
                s[6] = (short)f2bf(u1.z); s[7] = (short)f2bf(u1.w);
                *(short8_t*)&As[bufi][row * BK + kp] = s;
            }
        } else {
            const ushort* Ab = (const ushort*)Az;
            #pragma unroll
            for (int h = 0; h < 2; h++) {
                const int c = wid * 2 + h;       // 1KB chunk; dest = base + lane*16
                const int row = c * 16 + (lane >> 2);
                const int kh  = (lane & 3) * 8;
                gload_lds16(&Ab[(size_t)(m0 + row) * lda + k0 + kh],
                            (char*)&As[bufi][0] + c * 1024);
            }
        }
        #pragma unroll
        for (int h = 0; h < 2; h++) {
            const int c = wid * 2 + h;
            const int row = c * 16 + (lane >> 2);
            const int kh  = (lane & 3) * 8;
            gload_lds16(&B[(size_t)(n0 + row) * ldb + k0 + kh],
                        (char*)&Bs[bufi][0] + c * 1024);
        }
    };

    STAGE(0, 0);
    __syncthreads();                 // tile 0 ready

    for (int t = 0; t < nt; t++) {
        const int cur = t & 1;
        if (t + 1 < nt) STAGE(t + 1, cur ^ 1);   // issue-early: hides under MFMA

        const int frow = lane & 15;
        const int kh8  = (lane >> 4) * 8;
        short8_t a[4], b[4];
        #pragma unroll
        for (int mi = 0; mi < 4; mi++)
            a[mi] = *(const short8_t*)&As[cur][(wr * 64 + mi * 16 + frow) * BK + kh8];
        #pragma unroll
        for (int ni = 0; ni < 4; ni++)
            b[ni] = *(const short8_t*)&Bs[cur][(wc * 64 + ni * 16 + frow) * BK + kh8];
        #pragma unroll
        for (int mi = 0; mi < 4; mi++)
            #pragma unroll
            for (int ni = 0; ni < 4; ni++)
                acc[mi][ni] = __builtin_amdgcn_mfma_f32_16x16x32_bf16(
                    a[mi], b[ni], acc[mi][ni], 0, 0, 0);
        __syncthreads();   // drains vmcnt(0): next tile ready; reads done before overwrite
    }

    // ---- epilogue: D frag col=lane&15, row=(lane>>4)*4+reg ----
    const int col = lane & 15;
    const int rb  = (lane >> 4) * 4;
    #pragma unroll
    for (int mi = 0; mi < 4; mi++) {
        #pragma unroll
        for (int ni = 0; ni < 4; ni++) {
            const int r = m0 + wr * 64 + mi * 16 + rb;
            const int c = n0 + wc * 64 + ni * 16 + col;
            f32x4 v = acc[mi][ni];
            if (EPI == 0) {
                ushort* C = (ushort*)Cz;
                const float bz = bias[c];
                #pragma unroll
                for (int t = 0; t < 4; t++)
                    C[(size_t)(r + t) * ldc + c] = f2bf(v[t] + bz);
            } else if (EPI == 1) {
                float* C = (float*)Cz;
                #pragma unroll
                for (int t = 0; t < 4; t++)
                    C[(size_t)(r + t) * ldc + c] = v[t] * alpha;
            } else if (EPI == 2) {
                ushort* C = (ushort*)Cz;
                #pragma unroll
                for (int t = 0; t < 4; t++)
                    C[(size_t)(r + t) * ldc + c + off] = f2bf(v[t]);
            } else {
                float* C = (float*)Cz;
                const float bz = bias[c];
                #pragma unroll
                for (int t = 0; t < 4; t++)
                    C[(size_t)(r + t) * ldc + c] = v[t] + bz;
            }
        }
    }
}

// f32 -> bf16 cast (weights only), n4 = n/4
__global__ __launch_bounds__(TB)
void conv_f32_bf16(const float* __restrict__ in, ushort* __restrict__ out, int n4)
{
    for (int i = blockIdx.x * TB + threadIdx.x; i < n4; i += gridDim.x * TB) {
        float4 v = ((const float4*)in)[i];
        ushort4 o;
        o.x = f2bf(v.x); o.y = f2bf(v.y); o.z = f2bf(v.z); o.w = f2bf(v.w);
        ((ushort4*)out)[i] = o;
    }
}

// V [4096][ldv] -> Vt [1024][4096], bf16, 64x64 LDS tiles; batched via z
__global__ __launch_bounds__(TB)
void transposeV(const ushort* __restrict__ Vp, int ldv, ushort* __restrict__ Vtp,
                size_t strV, size_t strVt)
{
    const ushort* V = (const ushort*)((const char*)Vp + (size_t)blockIdx.z * strV);
    ushort* Vt = (ushort*)((char*)Vtp + (size_t)blockIdx.z * strVt);
    __shared__ ushort Ls[64][65];
    const int n0 = blockIdx.x * 64, d0 = blockIdx.y * 64;
    const int t = threadIdx.x;
    #pragma unroll
    for (int p = 0; p < 4; p++) {
        const int row = p * 16 + (t >> 4);
        const int c4 = (t & 15) * 4;
        ushort4 v = *(const ushort4*)&V[(size_t)(n0 + row) * ldv + d0 + c4];
        Ls[row][c4 + 0] = v.x; Ls[row][c4 + 1] = v.y;
        Ls[row][c4 + 2] = v.z; Ls[row][c4 + 3] = v.w;
    }
    __syncthreads();
    #pragma unroll
    for (int p = 0; p < 4; p++) {
        const int d = p * 16 + (t >> 4);
        const int n4 = (t & 15) * 4;
        ushort4 o;
        o.x = Ls[n4 + 0][d]; o.y = Ls[n4 + 1][d];
        o.z = Ls[n4 + 2][d]; o.w = Ls[n4 + 3][d];
        *(ushort4*)&Vt[(size_t)(d0 + d) * 4096 + n0 + n4] = o;
    }
}

// prefix-causal row softmax, batched: blockIdx.y = batch (stride CH rows).
// Row r = r0+blockIdx.x; compute over [0,r]; bf16 P zero-padded to 128-boundary.
__global__ __launch_bounds__(TB)
void softmax_prefix(float* __restrict__ Sp, ushort* __restrict__ Pp, int r0)
{
    const int local = blockIdx.x;
    const int r = r0 + local;
    const int pe = ((r >> 7) << 7) + 128;
    const size_t rowoff = ((size_t)blockIdx.y * gridDim.x + local) * 4096;
    float* p = Sp + rowoff;
    ushort* q = Pp + rowoff;
    const int t = threadIdx.x;
    const int wv = t >> 6, ln = t & 63;
    __shared__ float red[4];

    float lm = -INFINITY;
    for (int k4 = t * 4; k4 < pe; k4 += 1024) {
        float4 v = *(const float4*)&p[k4];
        lm = (k4 + 0 <= r) ? fmaxf(lm, v.x) : lm;
        lm = (k4 + 1 <= r) ? fmaxf(lm, v.y) : lm;
        lm = (k4 + 2 <= r) ? fmaxf(lm, v.z) : lm;
        lm = (k4 + 3 <= r) ? fmaxf(lm, v.w) : lm;
    }
    #pragma unroll
    for (int m = 1; m < 64; m <<= 1) lm = fmaxf(lm, __shfl_xor(lm, m, 64));
    if (ln == 0) red[wv] = lm;
    __syncthreads();
    const float mx = fmaxf(fmaxf(red[0], red[1]), fmaxf(red[2], red[3]));
    __syncthreads();

    float ls = 0.f;
    for (int k4 = t * 4; k4 < pe; k4 += 1024) {
        float4 v = *(const float4*)&p[k4];
        float4 e;
        e.x = (k4 + 0 <= r) ? __expf(v.x - mx) : 0.f;
        e.y = (k4 + 1 <= r) ? __expf(v.y - mx) : 0.f;
        e.z = (k4 + 2 <= r) ? __expf(v.z - mx) : 0.f;
        e.w = (k4 + 3 <= r) ? __expf(v.w - mx) : 0.f;
        ls += e.x + e.y + e.z + e.w;
        *(float4*)&p[k4] = e;
    }
    #pragma unroll
    for (int m = 1; m < 64; m <<= 1) ls += __shfl_xor(ls, m, 64);
    if (ln == 0) red[wv] = ls;
    __syncthreads();
    const float inv = 1.0f / (red[0] + red[1] + red[2] + red[3]);
    for (int k4 = t * 4; k4 < pe; k4 += 1024) {
        float4 e = *(const float4*)&p[k4];
        ushort4 o;
        o.x = f2bf(e.x * inv); o.y = f2bf(e.y * inv);
        o.z = f2bf(e.z * inv); o.w = f2bf(e.w * inv);
        *(ushort4*)&q[k4] = o;
    }
}

extern "C" void kernel_launch(void* const* d_in, const int* in_sizes, int n_in,
                              void* d_out, int out_size, void* d_ws, size_t ws_size,
                              hipStream_t stream)
{
    const float* x    = (const float*)d_in[0];   // [4,4096,1024]
    const float* Wqkv = (const float*)d_in[1];   // [3072,1024]
    const float* bqkv = (const float*)d_in[2];   // [3072]
    const float* Wo   = (const float*)d_in[3];   // [1024,1024]
    const float* bo   = (const float*)d_in[4];   // [1024]
    float* out = (float*)d_out;                  // [4,4096,1024] f32

    dim3 blk(TB);
    const size_t B_QKV = (size_t)4096 * 3072;    // per-batch qkv elems
    const size_t B_VT  = (size_t)1024 * 4096;    // per-batch Vt / T elems

    // ---- Path A: fully batched (needs fixedA + 4*CH*4096*6 bytes) ----
    const size_t fixedA = ((size_t)3072 * 1024 + (size_t)1024 * 1024 +
                           4 * B_QKV + 4 * B_VT + 4 * B_VT) * 2;   // ~168 MiB
    int CHa = 4096;
    while (CHa > 512 && fixedA + (size_t)4 * CHa * 4096 * 6 > ws_size) CHa >>= 1;

    if (fixedA + (size_t)4 * CHa * 4096 * 6 <= ws_size) {
        ushort* Wq   = (ushort*)d_ws;                  // [3072][1024]
        ushort* Wob  = Wq   + (size_t)3072 * 1024;     // [1024][1024]
        ushort* qkvA = Wob  + (size_t)1024 * 1024;     // [4][4096][3072]
        ushort* VtA  = qkvA + 4 * B_QKV;               // [4][1024][4096]
        ushort* TA   = VtA  + 4 * B_VT;                // [4][1024][4096]
        ushort* Pch  = TA   + 4 * B_VT;                // [4][CH][4096] bf16
        float*  Sch  = (float*)(Pch + (size_t)4 * CHa * 4096);  // [4][CH][4096] f32

        conv_f32_bf16<<<256, blk, 0, stream>>>(Wqkv, Wq,  3072 * 1024 / 4);
        conv_f32_bf16<<<128, blk, 0, stream>>>(Wo,   Wob, 1024 * 1024 / 4);

        // 1) qkv = x @ Wqkv^T + bqkv   (one GEMM, M=16384)
        gemm_bf16<1, 0, false, false, false><<<dim3(24, 128), blk, 0, stream>>>(
            x, 1024, Wq, 1024, bqkv, qkvA, 3072, 1024, 1.f, 0, 0, 0, 0);

        // V -> Vt, all batches
        transposeV<<<dim3(64, 16, 4), blk, 0, stream>>>(
            qkvA + 2048, 3072, VtA, B_QKV * 2, B_VT * 2);

        for (int r0 = 0; r0 < 4096; r0 += CHa) {
            // 2) S = 0.125 * Q K^T  (z=4; triangular blocks only)
            gemm_bf16<0, 1, true, false, false><<<dim3(32, CHa / 128, 4), blk, 0, stream>>>(
                qkvA + (size_t)r0 * 3072, 3072, qkvA + 1024, 3072, nullptr,
                Sch, 4096, 1024, 0.125f, r0,
                B_QKV * 2, B_QKV * 2, (size_t)CHa * 4096 * 4);
            // 3) P = prefix-softmax(S) -> bf16
            softmax_prefix<<<dim3(CHa, 4), blk, 0, stream>>>(Sch, Pch, r0);
            // 4) O_t[:, r0:r0+CH] = Vt @ P^T  (z=4; longest-K blocks first)
            gemm_bf16<0, 2, false, true, true><<<dim3(CHa / 128, 8, 4), blk, 0, stream>>>(
                VtA, 4096, Pch, 4096, nullptr, TA, 4096, 4096, 1.f, r0,
                B_VT * 2, (size_t)CHa * 4096 * 2, B_VT * 2);
        }

        // 5) out = T @ Wo^T + bo  (one GEMM, M=16384)
        gemm_bf16<0, 3, false, false, false><<<dim3(8, 128), blk, 0, stream>>>(
            TA, 1024, Wob, 1024, bo, out, 1024, 1024, 1.f, 0, 0, 0, 0);
        return;
    }

    // ---- Path B: per-batch fallback (Round-4 structure, ~80 MiB min) ----
    ushort* Wq   = (ushort*)d_ws;                       // 3072*1024
    ushort* Wob  = Wq   + (size_t)3072 * 1024;          // 1024*1024
    ushort* qkvb = Wob  + (size_t)1024 * 1024;          // 4096*3072
    ushort* Vtb  = qkvb + B_QKV;                        // 1024*4096
    ushort* Tall = Vtb  + B_VT;                         // 4*4096*1024
    ushort* Pch  = Tall + (size_t)4 * 4096 * 1024;      // CH*4096 bf16
    const size_t fixedB = ((size_t)3072 * 1024 + (size_t)1024 * 1024 +
                           B_QKV + B_VT + (size_t)4 * 4096 * 1024) * 2;
    int CH = 4096;
    while (CH > 128 && fixedB + (size_t)CH * 4096 * 6 > ws_size) CH >>= 1;
    float* Sch = (float*)(Pch + (size_t)CH * 4096);     // CH*4096 f32

    conv_f32_bf16<<<256, blk, 0, stream>>>(Wqkv, Wq,  3072 * 1024 / 4);
    conv_f32_bf16<<<128, blk, 0, stream>>>(Wo,   Wob, 1024 * 1024 / 4);

    for (int b = 0; b < 4; b++) {
        const float* xb = x + (size_t)b * 4096 * 1024;
        gemm_bf16<1, 0, false, false, false><<<dim3(24, 32), blk, 0, stream>>>(
            xb, 1024, Wq, 1024, bqkv, qkvb, 3072, 1024, 1.f, 0, 0, 0, 0);
        transposeV<<<dim3(64, 16), blk, 0, stream>>>(qkvb + 2048, 3072, Vtb, 0, 0);

        for (int r0 = 0; r0 < 4096; r0 += CH) {
            gemm_bf16<0, 1, true, false, false><<<dim3(32, CH / 128), blk, 0, stream>>>(
                qkvb + (size_t)r0 * 3072, 3072, qkvb + 1024, 3072, nullptr,
                Sch, 4096, 1024, 0.125f, r0, 0, 0, 0);
            softmax_prefix<<<dim3(CH, 1), blk, 0, stream>>>(Sch, Pch, r0);
            gemm_bf16<0, 2, false, true, true><<<dim3(CH / 128, 8), blk, 0, stream>>>(
                Vtb, 4096, Pch, 4096, nullptr,
                Tall + (size_t)b * 4096 * 1024, 4096, 4096, 1.f, r0, 0, 0, 0);
        }
    }

    gemm_bf16<0, 3, false, false, false><<<dim3(8, 128), blk, 0, stream>>>(
        Tall, 1024, Wob, 1024, bo, out, 1024, 1024, 1.f, 0, 0, 0, 0);
}

// Round 6
// 860.091 us; speedup vs baseline: 1.1152x; 1.1152x over previous
//
#include <hip/hip_runtime.h>
#include <math.h>

#define TB 256

typedef __attribute__((ext_vector_type(8))) short short8_t;
typedef __attribute__((ext_vector_type(4))) float f32x4;

__device__ __forceinline__ ushort f2bf(float f) {
    uint u = __float_as_uint(f);
    return (ushort)((u + 0x7FFFu + ((u >> 16) & 1u)) >> 16);  // RNE
}

__device__ __forceinline__ void gload_lds16(const void* g, void* l) {
    __builtin_amdgcn_global_load_lds(
        (const __attribute__((address_space(1))) void*)g,
        (__attribute__((address_space(3))) void*)l, 16, 0, 0);
}

// C[M x Nc] = A * B^T, bf16 in, f32 MFMA acc, 128x128x32 tiles.
// 3-slot LDS pipeline, counted vmcnt (T3/T4-lite): stage t+2, compute t,
// then s_waitcnt vmcnt(4) BEFORE s_barrier (t+1 ready; t+2 stays in flight).
// EPI 0: bf16 C = acc + bias[col]      (QKV)
// EPI 1: f32  C = acc * alpha          (S; softmax applies causal mask)
// EPI 2: bf16 C = acc, cols at +off    (PV -> T)
// EPI 3: f32  C = acc + bias[col]      (proj)
// TRI : causal block skip: return if n0 > m0+off+127
// KLIM: kend = min(K, n0+off+BN)       (PV causal k-limit)
// REVX: reverse blockIdx.x (longest-K blocks dispatch first)
template<int EPI, bool TRI, bool KLIM, bool REVX>
__global__ __launch_bounds__(TB)
void gemm_bf16(const ushort* __restrict__ A, int lda,
               const ushort* __restrict__ B, int ldb,
               const float* __restrict__ bias,
               void* __restrict__ Cv, int ldc,
               int K, float alpha, int off)
{
    constexpr int BM = 128, BN = 128, BK = 32;
    const int m0 = blockIdx.y * BM;
    const int nb = REVX ? (gridDim.x - 1 - blockIdx.x) : blockIdx.x;
    const int n0 = nb * BN;
    if (TRI && n0 > m0 + off + BM - 1) return;   // fully-masked causal block

    const int tid = threadIdx.x;
    const int lane = tid & 63;
    const int wid = tid >> 6;
    const int wr = wid >> 1, wc = wid & 1;       // wave -> 64x64 quadrant

    __shared__ __align__(16) ushort As[3][BM * BK];   // 3 x 8 KB
    __shared__ __align__(16) ushort Bs[3][BN * BK];   // 3 x 8 KB

    f32x4 acc[4][4];
    const f32x4 zero = {0.f, 0.f, 0.f, 0.f};
    #pragma unroll
    for (int mi = 0; mi < 4; mi++)
        #pragma unroll
        for (int ni = 0; ni < 4; ni++) acc[mi][ni] = zero;

    const int klim = KLIM ? (n0 + off + BN) : K;
    const int kend = klim < K ? klim : K;
    const int nt = kend / BK;

    // per STAGE: 4 vmem ops/thread (2 A-chunks + 2 B-chunks)
    auto STAGE = [&](int t, int s) {
        const int k0 = t * BK;
        const int c = wid * 2;                  // wave-uniform chunk base
        const int row0 = c * 16 + (lane >> 2);
        const int row1 = row0 + 16;
        const int kh = (lane & 3) * 8;
        gload_lds16(&A[(size_t)(m0 + row0) * lda + k0 + kh], (char*)&As[s][0] + c * 1024);
        gload_lds16(&A[(size_t)(m0 + row1) * lda + k0 + kh], (char*)&As[s][0] + (c + 1) * 1024);
        gload_lds16(&B[(size_t)(n0 + row0) * ldb + k0 + kh], (char*)&Bs[s][0] + c * 1024);
        gload_lds16(&B[(size_t)(n0 + row1) * ldb + k0 + kh], (char*)&Bs[s][0] + (c + 1) * 1024);
    };

    // prologue: fill slots 0,1; wait tile0 only
    STAGE(0, 0);
    if (nt > 1) {
        STAGE(1, 1);
        asm volatile("s_waitcnt vmcnt(4)" ::: "memory");
    } else {
        asm volatile("s_waitcnt vmcnt(0)" ::: "memory");
    }
    __builtin_amdgcn_s_barrier();

    for (int t = 0; t < nt; t++) {
        const int cur = t % 3;
        if (t + 2 < nt) STAGE(t + 2, (t + 2) % 3);   // 8 in flight

        const int frow = lane & 15;
        const int kh8  = (lane >> 4) * 8;
        short8_t a[4], b[4];
        #pragma unroll
        for (int mi = 0; mi < 4; mi++)
            a[mi] = *(const short8_t*)&As[cur][(wr * 64 + mi * 16 + frow) * BK + kh8];
        #pragma unroll
        for (int ni = 0; ni < 4; ni++)
            b[ni] = *(const short8_t*)&Bs[cur][(wc * 64 + ni * 16 + frow) * BK + kh8];
        #pragma unroll
        for (int mi = 0; mi < 4; mi++)
            #pragma unroll
            for (int ni = 0; ni < 4; ni++)
                acc[mi][ni] = __builtin_amdgcn_mfma_f32_16x16x32_bf16(
                    a[mi], b[ni], acc[mi][ni], 0, 0, 0);

        if (t + 1 < nt) {
            // own t+1 loads landed BEFORE barrier => tile t+1 globally ready after it;
            // t+2's 4 loads stay in flight across the barrier.
            if (t + 2 < nt) asm volatile("s_waitcnt vmcnt(4)" ::: "memory");
            else            asm volatile("s_waitcnt vmcnt(0)" ::: "memory");
            __builtin_amdgcn_s_barrier();
        }
    }

    // ---- epilogue: D frag col=lane&15, row=(lane>>4)*4+reg ----
    const int col = lane & 15;
    const int rb  = (lane >> 4) * 4;
    #pragma unroll
    for (int mi = 0; mi < 4; mi++) {
        #pragma unroll
        for (int ni = 0; ni < 4; ni++) {
            const int r = m0 + wr * 64 + mi * 16 + rb;
            const int c = n0 + wc * 64 + ni * 16 + col;
            f32x4 v = acc[mi][ni];
            if (EPI == 0) {
                ushort* C = (ushort*)Cv;
                const float bz = bias[c];
                #pragma unroll
                for (int t = 0; t < 4; t++)
                    C[(size_t)(r + t) * ldc + c] = f2bf(v[t] + bz);
            } else if (EPI == 1) {
                float* C = (float*)Cv;
                #pragma unroll
                for (int t = 0; t < 4; t++)
                    C[(size_t)(r + t) * ldc + c] = v[t] * alpha;
            } else if (EPI == 2) {
                ushort* C = (ushort*)Cv;
                #pragma unroll
                for (int t = 0; t < 4; t++)
                    C[(size_t)(r + t) * ldc + c + off] = f2bf(v[t]);
            } else {
                float* C = (float*)Cv;
                const float bz = bias[c];
                #pragma unroll
                for (int t = 0; t < 4; t++)
                    C[(size_t)(r + t) * ldc + c] = v[t] + bz;
            }
        }
    }
}

// f32 -> bf16 cast, n4 = n/4
__global__ __launch_bounds__(TB)
void conv_f32_bf16(const float* __restrict__ in, ushort* __restrict__ out, int n4)
{
    for (int i = blockIdx.x * TB + threadIdx.x; i < n4; i += gridDim.x * TB) {
        float4 v = ((const float4*)in)[i];
        ushort4 o;
        o.x = f2bf(v.x); o.y = f2bf(v.y); o.z = f2bf(v.z); o.w = f2bf(v.w);
        ((ushort4*)out)[i] = o;
    }
}

// V [4096][ldv] -> Vt [1024][4096], bf16, 64x64 LDS tiles
__global__ __launch_bounds__(TB)
void transposeV(const ushort* __restrict__ V, int ldv, ushort* __restrict__ Vt)
{
    __shared__ ushort Ls[64][65];
    const int n0 = blockIdx.x * 64, d0 = blockIdx.y * 64;
    const int t = threadIdx.x;
    #pragma unroll
    for (int p = 0; p < 4; p++) {
        const int row = p * 16 + (t >> 4);
        const int c4 = (t & 15) * 4;
        ushort4 v = *(const ushort4*)&V[(size_t)(n0 + row) * ldv + d0 + c4];
        Ls[row][c4 + 0] = v.x; Ls[row][c4 + 1] = v.y;
        Ls[row][c4 + 2] = v.z; Ls[row][c4 + 3] = v.w;
    }
    __syncthreads();
    #pragma unroll
    for (int p = 0; p < 4; p++) {
        const int d = p * 16 + (t >> 4);
        const int n4 = (t & 15) * 4;
        ushort4 o;
        o.x = Ls[n4 + 0][d]; o.y = Ls[n4 + 1][d];
        o.z = Ls[n4 + 2][d]; o.w = Ls[n4 + 3][d];
        *(ushort4*)&Vt[(size_t)(d0 + d) * 4096 + n0 + n4] = o;
    }
}

// prefix-causal row softmax: row r = r0+blockIdx.x over [0,r]; bf16 out,
// zero-padded to the 128-boundary (PV reads k < n0+off+128).
__global__ __launch_bounds__(TB)
void softmax_prefix(float* __restrict__ Sp, ushort* __restrict__ Pp, int r0)
{
    const int local = blockIdx.x;
    const int r = r0 + local;
    const int pe = ((r >> 7) << 7) + 128;
    float* p = Sp + (size_t)local * 4096;
    ushort* q = Pp + (size_t)local * 4096;
    const int t = threadIdx.x;
    const int wv = t >> 6, ln = t & 63;
    __shared__ float red[4];

    float lm = -INFINITY;
    for (int k4 = t * 4; k4 < pe; k4 += 1024) {
        float4 v = *(const float4*)&p[k4];
        lm = (k4 + 0 <= r) ? fmaxf(lm, v.x) : lm;
        lm = (k4 + 1 <= r) ? fmaxf(lm, v.y) : lm;
        lm = (k4 + 2 <= r) ? fmaxf(lm, v.z) : lm;
        lm = (k4 + 3 <= r) ? fmaxf(lm, v.w) : lm;
    }
    #pragma unroll
    for (int m = 1; m < 64; m <<= 1) lm = fmaxf(lm, __shfl_xor(lm, m, 64));
    if (ln == 0) red[wv] = lm;
    __syncthreads();
    const float mx = fmaxf(fmaxf(red[0], red[1]), fmaxf(red[2], red[3]));
    __syncthreads();

    float ls = 0.f;
    for (int k4 = t * 4; k4 < pe; k4 += 1024) {
        float4 v = *(const float4*)&p[k4];
        float4 e;
        e.x = (k4 + 0 <= r) ? __expf(v.x - mx) : 0.f;
        e.y = (k4 + 1 <= r) ? __expf(v.y - mx) : 0.f;
        e.z = (k4 + 2 <= r) ? __expf(v.z - mx) : 0.f;
        e.w = (k4 + 3 <= r) ? __expf(v.w - mx) : 0.f;
        ls += e.x + e.y + e.z + e.w;
        *(float4*)&p[k4] = e;
    }
    #pragma unroll
    for (int m = 1; m < 64; m <<= 1) ls += __shfl_xor(ls, m, 64);
    if (ln == 0) red[wv] = ls;
    __syncthreads();
    const float inv = 1.0f / (red[0] + red[1] + red[2] + red[3]);
    for (int k4 = t * 4; k4 < pe; k4 += 1024) {
        float4 e = *(const float4*)&p[k4];
        ushort4 o;
        o.x = f2bf(e.x * inv); o.y = f2bf(e.y * inv);
        o.z = f2bf(e.z * inv); o.w = f2bf(e.w * inv);
        *(ushort4*)&q[k4] = o;
    }
}

extern "C" void kernel_launch(void* const* d_in, const int* in_sizes, int n_in,
                              void* d_out, int out_size, void* d_ws, size_t ws_size,
                              hipStream_t stream)
{
    const float* x    = (const float*)d_in[0];   // [4,4096,1024]
    const float* Wqkv = (const float*)d_in[1];   // [3072,1024]
    const float* bqkv = (const float*)d_in[2];   // [3072]
    const float* Wo   = (const float*)d_in[3];   // [1024,1024]
    const float* bo   = (const float*)d_in[4];   // [1024]
    float* out = (float*)d_out;                  // [4,4096,1024] f32

    // ---- workspace (bf16 elems unless noted) ----
    // xbf 33.5 + Wq 6.3 + Wob 2.1 + qkvb 25.2 + Vtb 8.4 + Tall 33.5 = 109 MB fixed
    // + S (CH*4096*4) + P (CH*4096*2): CH=4096 -> 210 MB total
    ushort* xbf  = (ushort*)d_ws;                       // [4][4096][1024]
    ushort* Wq   = xbf  + (size_t)4 * 4096 * 1024;      // [3072][1024]
    ushort* Wob  = Wq   + (size_t)3072 * 1024;          // [1024][1024]
    ushort* qkvb = Wob  + (size_t)1024 * 1024;          // [4096][3072] per-batch
    ushort* Vtb  = qkvb + (size_t)4096 * 3072;          // [1024][4096] per-batch
    ushort* Tall = Vtb  + (size_t)1024 * 4096;          // [4][1024][4096]
    ushort* Pch  = Tall + (size_t)4 * 4096 * 1024;      // [CH][4096] bf16
    const size_t fixedB = ((size_t)4 * 4096 * 1024 + (size_t)3072 * 1024 +
                           (size_t)1024 * 1024 + (size_t)4096 * 3072 +
                           (size_t)1024 * 4096 + (size_t)4 * 4096 * 1024) * 2;
    int CH = 4096;
    while (CH > 128 && fixedB + (size_t)CH * 4096 * 6 > ws_size) CH >>= 1;
    float* Sch = (float*)(Pch + (size_t)CH * 4096);     // [CH][4096] f32

    dim3 blk(TB);

    conv_f32_bf16<<<2048, blk, 0, stream>>>(x,    xbf, 4 * 4096 * 1024 / 4);
    conv_f32_bf16<<<256,  blk, 0, stream>>>(Wqkv, Wq,  3072 * 1024 / 4);
    conv_f32_bf16<<<128,  blk, 0, stream>>>(Wo,   Wob, 1024 * 1024 / 4);

    for (int b = 0; b < 4; b++) {
        const ushort* xb = xbf + (size_t)b * 4096 * 1024;
        // 1) qkv_b = x_b @ Wqkv^T + bqkv   (768 blocks, 3/CU)
        gemm_bf16<0, false, false, false><<<dim3(24, 32), blk, 0, stream>>>(
            xb, 1024, Wq, 1024, bqkv, qkvb, 3072, 1024, 1.f, 0);

        transposeV<<<dim3(64, 16), blk, 0, stream>>>(qkvb + 2048, 3072, Vtb);

        for (int r0 = 0; r0 < 4096; r0 += CH) {
            // 2) S = 0.125 * Q K^T (triangular blocks only; 528 blocks at CH=4096)
            gemm_bf16<1, true, false, false><<<dim3(32, CH / 128), blk, 0, stream>>>(
                qkvb + (size_t)r0 * 3072, 3072, qkvb + 1024, 3072, nullptr,
                Sch, 4096, 1024, 0.125f, r0);
            // 3) P = prefix-softmax(S) -> bf16
            softmax_prefix<<<dim3(CH), blk, 0, stream>>>(Sch, Pch, r0);
            // 4) O_t[:, r0:r0+CH] = Vt @ P^T  (causal k-limit; longest first)
            gemm_bf16<2, false, true, true><<<dim3(CH / 128, 8), blk, 0, stream>>>(
                Vtb, 4096, Pch, 4096, nullptr,
                Tall + (size_t)b * 4096 * 1024, 4096, 4096, 1.f, r0);
        }
    }

    // 5) out = T @ Wo^T + bo  (one GEMM, M=16384, 1024 blocks)
    gemm_bf16<3, false, false, false><<<dim3(8, 128), blk, 0, stream>>>(
        Tall, 1024, Wob, 1024, bo, out, 1024, 1024, 1.f, 0);
}

// Round 7
// 852.842 us; speedup vs baseline: 1.1247x; 1.0085x over previous
//
#include <hip/hip_runtime.h>
#include <math.h>

#define TB 256

typedef __attribute__((ext_vector_type(8))) short short8_t;
typedef __attribute__((ext_vector_type(4))) float f32x4;

__device__ __forceinline__ ushort f2bf(float f) {
    uint u = __float_as_uint(f);
    return (ushort)((u + 0x7FFFu + ((u >> 16) & 1u)) >> 16);  // RNE
}

__device__ __forceinline__ void gload_lds16(const void* g, void* l) {
    __builtin_amdgcn_global_load_lds(
        (const __attribute__((address_space(1))) void*)g,
        (__attribute__((address_space(3))) void*)l, 16, 0, 0);
}

// C[M x Nc] = A * B^T, bf16 MFMA 16x16x32, f32 acc, 128x128x32 tiles.
// 3-slot LDS pipeline with counted vmcnt (loads for t+2 stay in flight
// across the barrier; wait only for t+1's).
// CONV 1: A f32, reg-staged + converted (vmem from A drains via reg deps ->
//         only B's 2 global_load_lds counted; lgkmcnt(0) before barriers).
// CONV 0: A bf16 via global_load_lds (4 vmem/STAGE counted).
// EPI 0: bf16 C = acc + bias[col]      (QKV)
// EPI 1: f32  C = acc * alpha          (S and PV partials)
// EPI 3: f32  C = acc + bias[col]      (proj)
// TRI  : causal block skip: return if n0 > m0+off+127
// KLIM : kend = min(K, n0+off+BN)      (PV causal k-limit)
// REVX : reverse blockIdx.x (longest-K blocks dispatch first)
// SPLITK: blockIdx.z in {0,1} splits [0,nt) into halves; C += z*1024*4096 f32
template<int CONV, int EPI, bool TRI, bool KLIM, bool REVX, bool SPLITK>
__global__ __launch_bounds__(TB)
void gemm_bf16(const void* __restrict__ Av, int lda,
               const ushort* __restrict__ B, int ldb,
               const float* __restrict__ bias,
               void* __restrict__ Cv, int ldc,
               int K, float alpha, int off)
{
    constexpr int BM = 128, BN = 128, BK = 32;
    const int m0 = blockIdx.y * BM;
    const int nb = REVX ? (gridDim.x - 1 - blockIdx.x) : blockIdx.x;
    const int n0 = nb * BN;
    if (TRI && n0 > m0 + off + BM - 1) return;   // fully-masked causal block

    const int tid = threadIdx.x;
    const int lane = tid & 63;
    const int wid = tid >> 6;
    const int wr = wid >> 1, wc = wid & 1;       // wave -> 64x64 quadrant

    __shared__ __align__(16) ushort As[3][BM * BK];   // 3 x 8 KB
    __shared__ __align__(16) ushort Bs[3][BN * BK];   // 3 x 8 KB

    f32x4 acc[4][4];
    const f32x4 zero = {0.f, 0.f, 0.f, 0.f};
    #pragma unroll
    for (int mi = 0; mi < 4; mi++)
        #pragma unroll
        for (int ni = 0; ni < 4; ni++) acc[mi][ni] = zero;

    const int klim = KLIM ? (n0 + off + BN) : K;
    const int kend = klim < K ? klim : K;
    const int ntf = kend / BK;
    int t0 = 0, t1 = ntf;
    if (SPLITK) {
        const int half = (ntf + 1) >> 1;
        if (blockIdx.z == 0) t1 = half; else t0 = half;
    }
    const int ntl = t1 - t0;

    auto STAGE = [&](int t, int s) {
        const int k0 = t * BK;
        if (CONV) {
            const float* Af = (const float*)Av;
            #pragma unroll
            for (int h = 0; h < 2; h++) {
                const int q = tid + h * TB;      // 0..511
                const int row = q >> 2;          // 0..127
                const int kp = (q & 3) * 8;      // 0,8,16,24
                const float* src = &Af[(size_t)(m0 + row) * lda + k0 + kp];
                float4 u0 = *(const float4*)src;
                float4 u1 = *(const float4*)(src + 4);
                short8_t sv;
                sv[0] = (short)f2bf(u0.x); sv[1] = (short)f2bf(u0.y);
                sv[2] = (short)f2bf(u0.z); sv[3] = (short)f2bf(u0.w);
                sv[4] = (short)f2bf(u1.x); sv[5] = (short)f2bf(u1.y);
                sv[6] = (short)f2bf(u1.z); sv[7] = (short)f2bf(u1.w);
                *(short8_t*)&As[s][row * BK + kp] = sv;
            }
        } else {
            const ushort* Ab = (const ushort*)Av;
            const int c = wid * 2;               // wave-uniform chunk base
            const int row0 = c * 16 + (lane >> 2);
            const int row1 = row0 + 16;
            const int kh = (lane & 3) * 8;
            gload_lds16(&Ab[(size_t)(m0 + row0) * lda + k0 + kh],
                        (char*)&As[s][0] + c * 1024);
            gload_lds16(&Ab[(size_t)(m0 + row1) * lda + k0 + kh],
                        (char*)&As[s][0] + (c + 1) * 1024);
        }
        const int c = wid * 2;
        const int row0 = c * 16 + (lane >> 2);
        const int row1 = row0 + 16;
        const int kh = (lane & 3) * 8;
        gload_lds16(&B[(size_t)(n0 + row0) * ldb + k0 + kh],
                    (char*)&Bs[s][0] + c * 1024);
        gload_lds16(&B[(size_t)(n0 + row1) * ldb + k0 + kh],
                    (char*)&Bs[s][0] + (c + 1) * 1024);
    };

    auto wait_pipe = [&]() {   // t+1's loads done; t+2's stay in flight
        if constexpr (CONV != 0) asm volatile("s_waitcnt vmcnt(2)" ::: "memory");
        else                     asm volatile("s_waitcnt vmcnt(4)" ::: "memory");
    };
    auto wait_zero = [&]() { asm volatile("s_waitcnt vmcnt(0)" ::: "memory"); };
    auto wait_lgkm = [&]() {   // CONV: drain A ds_writes before barrier
        if constexpr (CONV != 0) asm volatile("s_waitcnt lgkmcnt(0)" ::: "memory");
    };

    // prologue: fill slots 0,1; wait for tile t0 only
    STAGE(t0, 0);
    if (ntl > 1) { STAGE(t0 + 1, 1); wait_pipe(); }
    else         { wait_zero(); }
    wait_lgkm();
    __builtin_amdgcn_s_barrier();

    const int frow = lane & 15;
    const int kh8  = (lane >> 4) * 8;

    for (int u = 0; u < ntl; u++) {
        const int cur = u % 3;
        if (u + 2 < ntl) STAGE(t0 + u + 2, (u + 2) % 3);

        short8_t a[4], b[4];
        #pragma unroll
        for (int mi = 0; mi < 4; mi++)
            a[mi] = *(const short8_t*)&As[cur][(wr * 64 + mi * 16 + frow) * BK + kh8];
        #pragma unroll
        for (int ni = 0; ni < 4; ni++)
            b[ni] = *(const short8_t*)&Bs[cur][(wc * 64 + ni * 16 + frow) * BK + kh8];
        #pragma unroll
        for (int mi = 0; mi < 4; mi++)
            #pragma unroll
            for (int ni = 0; ni < 4; ni++)
                acc[mi][ni] = __builtin_amdgcn_mfma_f32_16x16x32_bf16(
                    a[mi], b[ni], acc[mi][ni], 0, 0, 0);

        if (u + 1 < ntl) {
            if (u + 2 < ntl) wait_pipe();
            else             wait_zero();
            wait_lgkm();
            __builtin_amdgcn_s_barrier();
        }
    }

    // ---- epilogue: D frag col=lane&15, row=(lane>>4)*4+reg ----
    void* Czv = Cv;
    if (SPLITK)
        Czv = (void*)((float*)Cv + (size_t)blockIdx.z * 1024 * 4096);
    const int col = lane & 15;
    const int rb  = (lane >> 4) * 4;
    #pragma unroll
    for (int mi = 0; mi < 4; mi++) {
        #pragma unroll
        for (int ni = 0; ni < 4; ni++) {
            const int r = m0 + wr * 64 + mi * 16 + rb;
            const int c = n0 + wc * 64 + ni * 16 + col;
            f32x4 v = acc[mi][ni];
            if (EPI == 0) {
                ushort* C = (ushort*)Czv;
                const float bz = bias[c];
                #pragma unroll
                for (int t = 0; t < 4; t++)
                    C[(size_t)(r + t) * ldc + c] = f2bf(v[t] + bz);
            } else if (EPI == 1) {
                float* C = (float*)Czv;
                #pragma unroll
                for (int t = 0; t < 4; t++)
                    C[(size_t)(r + t) * ldc + c] = v[t] * alpha;
            } else {
                float* C = (float*)Czv;
                const float bz = bias[c];
                #pragma unroll
                for (int t = 0; t < 4; t++)
                    C[(size_t)(r + t) * ldc + c] = v[t] + bz;
            }
        }
    }
}

// f32 -> bf16 cast (weights only), n4 = n/4
__global__ __launch_bounds__(TB)
void conv_f32_bf16(const float* __restrict__ in, ushort* __restrict__ out, int n4)
{
    for (int i = blockIdx.x * TB + threadIdx.x; i < n4; i += gridDim.x * TB) {
        float4 v = ((const float4*)in)[i];
        ushort4 o;
        o.x = f2bf(v.x); o.y = f2bf(v.y); o.z = f2bf(v.z); o.w = f2bf(v.w);
        ((ushort4*)out)[i] = o;
    }
}

// Tall_b[d][n] = bf16(Tpart0[d][n] + Tpart1[d][n]); n4 = elems/4
__global__ __launch_bounds__(TB)
void reduce_pair_bf16(const float* __restrict__ a, const float* __restrict__ b,
                      ushort* __restrict__ o, int n4)
{
    for (int i = blockIdx.x * TB + threadIdx.x; i < n4; i += gridDim.x * TB) {
        float4 x = ((const float4*)a)[i];
        float4 y = ((const float4*)b)[i];
        ushort4 z;
        z.x = f2bf(x.x + y.x); z.y = f2bf(x.y + y.y);
        z.z = f2bf(x.z + y.z); z.w = f2bf(x.w + y.w);
        ((ushort4*)o)[i] = z;
    }
}

// V [4096][ldv] -> Vt [1024][4096], bf16, 64x64 LDS tiles
__global__ __launch_bounds__(TB)
void transposeV(const ushort* __restrict__ V, int ldv, ushort* __restrict__ Vt)
{
    __shared__ ushort Ls[64][65];
    const int n0 = blockIdx.x * 64, d0 = blockIdx.y * 64;
    const int t = threadIdx.x;
    #pragma unroll
    for (int p = 0; p < 4; p++) {
        const int row = p * 16 + (t >> 4);
        const int c4 = (t & 15) * 4;
        ushort4 v = *(const ushort4*)&V[(size_t)(n0 + row) * ldv + d0 + c4];
        Ls[row][c4 + 0] = v.x; Ls[row][c4 + 1] = v.y;
        Ls[row][c4 + 2] = v.z; Ls[row][c4 + 3] = v.w;
    }
    __syncthreads();
    #pragma unroll
    for (int p = 0; p < 4; p++) {
        const int d = p * 16 + (t >> 4);
        const int n4 = (t & 15) * 4;
        ushort4 o;
        o.x = Ls[n4 + 0][d]; o.y = Ls[n4 + 1][d];
        o.z = Ls[n4 + 2][d]; o.w = Ls[n4 + 3][d];
        *(ushort4*)&Vt[(size_t)(d0 + d) * 4096 + n0 + n4] = o;
    }
}

// prefix-causal row softmax: row r = r0+blockIdx.x over [0,r]; bf16 out,
// zero-padded to the 128-boundary (PV reads k < n0+128).
__global__ __launch_bounds__(TB)
void softmax_prefix(float* __restrict__ Sp, ushort* __restrict__ Pp, int r0)
{
    const int local = blockIdx.x;
    const int r = r0 + local;
    const int pe = ((r >> 7) << 7) + 128;
    float* p = Sp + (size_t)local * 4096;
    ushort* q = Pp + (size_t)local * 4096;
    const int t = threadIdx.x;
    const int wv = t >> 6, ln = t & 63;
    __shared__ float red[4];

    float lm = -INFINITY;
    for (int k4 = t * 4; k4 < pe; k4 += 1024) {
        float4 v = *(const float4*)&p[k4];
        lm = (k4 + 0 <= r) ? fmaxf(lm, v.x) : lm;
        lm = (k4 + 1 <= r) ? fmaxf(lm, v.y) : lm;
        lm = (k4 + 2 <= r) ? fmaxf(lm, v.z) : lm;
        lm = (k4 + 3 <= r) ? fmaxf(lm, v.w) : lm;
    }
    #pragma unroll
    for (int m = 1; m < 64; m <<= 1) lm = fmaxf(lm, __shfl_xor(lm, m, 64));
    if (ln == 0) red[wv] = lm;
    __syncthreads();
    const float mx = fmaxf(fmaxf(red[0], red[1]), fmaxf(red[2], red[3]));
    __syncthreads();

    float ls = 0.f;
    for (int k4 = t * 4; k4 < pe; k4 += 1024) {
        float4 v = *(const float4*)&p[k4];
        float4 e;
        e.x = (k4 + 0 <= r) ? __expf(v.x - mx) : 0.f;
        e.y = (k4 + 1 <= r) ? __expf(v.y - mx) : 0.f;
        e.z = (k4 + 2 <= r) ? __expf(v.z - mx) : 0.f;
        e.w = (k4 + 3 <= r) ? __expf(v.w - mx) : 0.f;
        ls += e.x + e.y + e.z + e.w;
        *(float4*)&p[k4] = e;
    }
    #pragma unroll
    for (int m = 1; m < 64; m <<= 1) ls += __shfl_xor(ls, m, 64);
    if (ln == 0) red[wv] = ls;
    __syncthreads();
    const float inv = 1.0f / (red[0] + red[1] + red[2] + red[3]);
    for (int k4 = t * 4; k4 < pe; k4 += 1024) {
        float4 e = *(const float4*)&p[k4];
        ushort4 o;
        o.x = f2bf(e.x * inv); o.y = f2bf(e.y * inv);
        o.z = f2bf(e.z * inv); o.w = f2bf(e.w * inv);
        *(ushort4*)&q[k4] = o;
    }
}

extern "C" void kernel_launch(void* const* d_in, const int* in_sizes, int n_in,
                              void* d_out, int out_size, void* d_ws, size_t ws_size,
                              hipStream_t stream)
{
    const float* x    = (const float*)d_in[0];   // [4,4096,1024]
    const float* Wqkv = (const float*)d_in[1];   // [3072,1024]
    const float* bqkv = (const float*)d_in[2];   // [3072]
    const float* Wo   = (const float*)d_in[3];   // [1024,1024]
    const float* bo   = (const float*)d_in[4];   // [1024]
    float* out = (float*)d_out;                  // [4,4096,1024] f32

    // ---- workspace: 209.8 MB total (== R6 footprint, proven to fit) ----
    ushort* Wq    = (ushort*)d_ws;                      // [3072][1024]      6.3 MB
    ushort* Wob   = Wq    + (size_t)3072 * 1024;        // [1024][1024]      2.1 MB
    ushort* qkvb  = Wob   + (size_t)1024 * 1024;        // [4096][3072]     25.2 MB
    ushort* Vtb   = qkvb  + (size_t)4096 * 3072;        // [1024][4096]      8.4 MB
    ushort* Tall  = Vtb   + (size_t)1024 * 4096;        // [4][1024][4096]  33.6 MB
    ushort* Pch   = Tall  + (size_t)4 * 1024 * 4096;    // [4096][4096]     33.6 MB
    float*  Sch   = (float*)(Pch + (size_t)4096 * 4096);// [4096][4096] f32 67.1 MB
    float*  Tpart = Sch + (size_t)4096 * 4096;          // [2][1024][4096]  33.6 MB

    dim3 blk(TB);

    conv_f32_bf16<<<256, blk, 0, stream>>>(Wqkv, Wq,  3072 * 1024 / 4);
    conv_f32_bf16<<<128, blk, 0, stream>>>(Wo,   Wob, 1024 * 1024 / 4);

    for (int b = 0; b < 4; b++) {
        const float* xb = x + (size_t)b * 4096 * 1024;
        // 1) qkv_b = x_b @ Wqkv^T + bqkv  (CONV staging from f32 x; 768 blocks)
        gemm_bf16<1, 0, false, false, false, false><<<dim3(24, 32), blk, 0, stream>>>(
            xb, 1024, Wq, 1024, bqkv, qkvb, 3072, 1024, 1.f, 0);

        transposeV<<<dim3(64, 16), blk, 0, stream>>>(qkvb + 2048, 3072, Vtb);

        // 2) S = 0.125 * Q K^T (triangular blocks only; 528 blocks)
        gemm_bf16<0, 1, true, false, false, false><<<dim3(32, 32), blk, 0, stream>>>(
            qkvb, 3072, qkvb + 1024, 3072, nullptr, Sch, 4096, 1024, 0.125f, 0);

        // 3) P = prefix-softmax(S) -> bf16 (zero-padded to 128-boundary)
        softmax_prefix<<<dim3(4096), blk, 0, stream>>>(Sch, Pch, 0);

        // 4) PV split-K x2: Tpart[z][d][n] = Vt @ P^T over k-half z (512 blocks)
        gemm_bf16<0, 1, false, true, true, true><<<dim3(32, 8, 2), blk, 0, stream>>>(
            Vtb, 4096, Pch, 4096, nullptr, Tpart, 4096, 4096, 1.f, 0);

        // 4b) Tall_b = bf16(Tpart0 + Tpart1)
        reduce_pair_bf16<<<1024, blk, 0, stream>>>(
            Tpart, Tpart + (size_t)1024 * 4096,
            Tall + (size_t)b * 1024 * 4096, 1024 * 4096 / 4);
    }

    // 5) out = T @ Wo^T + bo  (one GEMM, M=16384, 1024 blocks)
    gemm_bf16<0, 3, false, false, false, false><<<dim3(8, 128), blk, 0, stream>>>(
        Tall, 1024, Wob, 1024, bo, out, 1024, 1024, 1.f, 0);
}

// Round 8
// 811.765 us; speedup vs baseline: 1.1816x; 1.0506x over previous
//
#include <hip/hip_runtime.h>
#include <math.h>

#define TB 256

typedef __attribute__((ext_vector_type(8))) short short8_t;
typedef __attribute__((ext_vector_type(4))) float f32x4;

__device__ __forceinline__ ushort f2bf(float f) {
    uint u = __float_as_uint(f);
    return (ushort)((u + 0x7FFFu + ((u >> 16) & 1u)) >> 16);  // RNE
}

__device__ __forceinline__ void gload_lds16(const void* g, void* l) {
    __builtin_amdgcn_global_load_lds(
        (const __attribute__((address_space(1))) void*)g,
        (__attribute__((address_space(3))) void*)l, 16, 0, 0);
}

// C[M x Nc] = A * B^T, bf16 in (global_load_lds staging), f32 MFMA acc.
// Tiles: BM x 128 x 32, 4 waves. BM=128: wave grid 2x2 (64x64 each).
//        BM=64 : wave grid 1x4 (64x32 each) -- small tile => 2x blocks (TLP).
// 3-slot LDS pipeline, counted vmcnt: wait t+1's loads, t+2's stay in flight.
// EPI 0: bf16 C = acc + bias[col]      (QKV)
// EPI 1: f32  C = acc * alpha          (S / PV partials)
// EPI 3: f32  C = acc + bias[col]      (proj)
// TRI  : causal block skip (return if n0 > m0+off+BM-1)
// KLIM : kend = min(K, n0+off+128)     (PV causal k-limit)
// REVX : reverse blockIdx.x (longest-K first)   REVY: reverse y (S packing)
// SPLITK: blockIdx.z halves [0,nt); C += z*1024*4096 floats
// XCD  : chunked XCD swizzle of linear block id (needs nwg%8==0)
template<int BM, int EPI, bool TRI, bool KLIM, bool REVX, bool REVY,
         bool SPLITK, bool XCD>
__global__ __launch_bounds__(TB)
void gemm_bf16(const ushort* __restrict__ A, int lda,
               const ushort* __restrict__ B, int ldb,
               const float* __restrict__ bias,
               void* __restrict__ Cv, int ldc,
               int K, float alpha, int off)
{
    constexpr int BN = 128, BK = 32;
    constexpr int NI = (BM == 128) ? 4 : 2;

    int bx = blockIdx.x, by = blockIdx.y;
    if (XCD) {
        const int gx = gridDim.x;
        const int nwg = gx * gridDim.y;
        const int lin = by * gx + bx;
        const int swz = (lin & 7) * (nwg >> 3) + (lin >> 3);
        bx = swz % gx; by = swz / gx;
    }
    const int m0 = (REVY ? (gridDim.y - 1 - by) : by) * BM;
    const int nb = REVX ? (gridDim.x - 1 - bx) : bx;
    const int n0 = nb * BN;
    if (TRI && n0 > m0 + off + BM - 1) return;   // fully-masked causal block

    const int tid = threadIdx.x;
    const int lane = tid & 63;
    const int wid = tid >> 6;
    const int arow = (BM == 128) ? (wid >> 1) * 64 : 0;
    const int bcol = (BM == 128) ? (wid & 1) * 64 : wid * 32;

    __shared__ __align__(16) ushort As[3][BM * BK];
    __shared__ __align__(16) ushort Bs[3][BN * BK];

    f32x4 acc[4][NI];
    const f32x4 zero = {0.f, 0.f, 0.f, 0.f};
    #pragma unroll
    for (int mi = 0; mi < 4; mi++)
        #pragma unroll
        for (int ni = 0; ni < NI; ni++) acc[mi][ni] = zero;

    const int klim = KLIM ? (n0 + off + BN) : K;
    const int kend = klim < K ? klim : K;
    const int ntf = kend / BK;
    int t0 = 0, t1 = ntf;
    if (SPLITK) {
        const int half = (ntf + 1) >> 1;
        if (blockIdx.z == 0) t1 = half; else t0 = half;
    }
    const int ntl = t1 - t0;

    auto STAGE = [&](int t, int s) {
        const int k0 = t * BK;
        const int kh = (lane & 3) * 8;
        const int rsub = lane >> 2;
        if constexpr (BM == 128) {
            const int c = wid * 2;
            gload_lds16(&A[(size_t)(m0 + c * 16 + rsub) * lda + k0 + kh],
                        (char*)&As[s][0] + c * 1024);
            gload_lds16(&A[(size_t)(m0 + c * 16 + 16 + rsub) * lda + k0 + kh],
                        (char*)&As[s][0] + (c + 1) * 1024);
        } else {
            const int c = wid;
            gload_lds16(&A[(size_t)(m0 + c * 16 + rsub) * lda + k0 + kh],
                        (char*)&As[s][0] + c * 1024);
        }
        const int cb = wid * 2;
        gload_lds16(&B[(size_t)(n0 + cb * 16 + rsub) * ldb + k0 + kh],
                    (char*)&Bs[s][0] + cb * 1024);
        gload_lds16(&B[(size_t)(n0 + cb * 16 + 16 + rsub) * ldb + k0 + kh],
                    (char*)&Bs[s][0] + (cb + 1) * 1024);
    };

    auto wait_pipe = [&]() {   // t+1's loads done; t+2's stay in flight
        if constexpr (BM == 128) asm volatile("s_waitcnt vmcnt(4)" ::: "memory");
        else                     asm volatile("s_waitcnt vmcnt(3)" ::: "memory");
    };
    auto wait_zero = [&]() { asm volatile("s_waitcnt vmcnt(0)" ::: "memory"); };

    STAGE(t0, 0);
    if (ntl > 1) { STAGE(t0 + 1, 1); wait_pipe(); }
    else         { wait_zero(); }
    __builtin_amdgcn_s_barrier();

    const int frow = lane & 15;
    const int kh8  = (lane >> 4) * 8;

    for (int u = 0; u < ntl; u++) {
        const int cur = u % 3;
        if (u + 2 < ntl) STAGE(t0 + u + 2, (u + 2) % 3);

        short8_t a[4], b[NI];
        #pragma unroll
        for (int mi = 0; mi < 4; mi++)
            a[mi] = *(const short8_t*)&As[cur][(arow + mi * 16 + frow) * BK + kh8];
        #pragma unroll
        for (int ni = 0; ni < NI; ni++)
            b[ni] = *(const short8_t*)&Bs[cur][(bcol + ni * 16 + frow) * BK + kh8];
        #pragma unroll
        for (int mi = 0; mi < 4; mi++)
            #pragma unroll
            for (int ni = 0; ni < NI; ni++)
                acc[mi][ni] = __builtin_amdgcn_mfma_f32_16x16x32_bf16(
                    a[mi], b[ni], acc[mi][ni], 0, 0, 0);

        if (u + 1 < ntl) {
            if (u + 2 < ntl) wait_pipe();
            else             wait_zero();
            __builtin_amdgcn_s_barrier();
        }
    }

    // ---- epilogue: D frag col=lane&15, row=(lane>>4)*4+reg ----
    void* Czv = Cv;
    if (SPLITK)
        Czv = (void*)((float*)Cv + (size_t)blockIdx.z * 1024 * 4096);
    const int col = lane & 15;
    const int rb  = (lane >> 4) * 4;
    #pragma unroll
    for (int mi = 0; mi < 4; mi++) {
        #pragma unroll
        for (int ni = 0; ni < NI; ni++) {
            const int r = m0 + arow + mi * 16 + rb;
            const int c = n0 + bcol + ni * 16 + col;
            f32x4 v = acc[mi][ni];
            if (EPI == 0) {
                ushort* C = (ushort*)Czv;
                const float bz = bias[c];
                #pragma unroll
                for (int t = 0; t < 4; t++)
                    C[(size_t)(r + t) * ldc + c] = f2bf(v[t] + bz);
            } else if (EPI == 1) {
                float* C = (float*)Czv;
                #pragma unroll
                for (int t = 0; t < 4; t++)
                    C[(size_t)(r + t) * ldc + c] = v[t] * alpha;
            } else {
                float* C = (float*)Czv;
                const float bz = bias[c];
                #pragma unroll
                for (int t = 0; t < 4; t++)
                    C[(size_t)(r + t) * ldc + c] = v[t] + bz;
            }
        }
    }
}

// f32 -> bf16 cast, n4 = n/4
__global__ __launch_bounds__(TB)
void conv_f32_bf16(const float* __restrict__ in, ushort* __restrict__ out, int n4)
{
    for (int i = blockIdx.x * TB + threadIdx.x; i < n4; i += gridDim.x * TB) {
        float4 v = ((const float4*)in)[i];
        ushort4 o;
        o.x = f2bf(v.x); o.y = f2bf(v.y); o.z = f2bf(v.z); o.w = f2bf(v.w);
        ((ushort4*)out)[i] = o;
    }
}

// Tall_b[i] = bf16(Tpart0[i] + Tpart1[i]); n4 = elems/4
__global__ __launch_bounds__(TB)
void reduce_pair_bf16(const float* __restrict__ a, const float* __restrict__ b,
                      ushort* __restrict__ o, int n4)
{
    for (int i = blockIdx.x * TB + threadIdx.x; i < n4; i += gridDim.x * TB) {
        float4 x = ((const float4*)a)[i];
        float4 y = ((const float4*)b)[i];
        ushort4 z;
        z.x = f2bf(x.x + y.x); z.y = f2bf(x.y + y.y);
        z.z = f2bf(x.z + y.z); z.w = f2bf(x.w + y.w);
        ((ushort4*)o)[i] = z;
    }
}

// V [4096][ldv] -> Vt [1024][4096], bf16, 64x64 LDS tiles
__global__ __launch_bounds__(TB)
void transposeV(const ushort* __restrict__ V, int ldv, ushort* __restrict__ Vt)
{
    __shared__ ushort Ls[64][65];
    const int n0 = blockIdx.x * 64, d0 = blockIdx.y * 64;
    const int t = threadIdx.x;
    #pragma unroll
    for (int p = 0; p < 4; p++) {
        const int row = p * 16 + (t >> 4);
        const int c4 = (t & 15) * 4;
        ushort4 v = *(const ushort4*)&V[(size_t)(n0 + row) * ldv + d0 + c4];
        Ls[row][c4 + 0] = v.x; Ls[row][c4 + 1] = v.y;
        Ls[row][c4 + 2] = v.z; Ls[row][c4 + 3] = v.w;
    }
    __syncthreads();
    #pragma unroll
    for (int p = 0; p < 4; p++) {
        const int d = p * 16 + (t >> 4);
        const int n4 = (t & 15) * 4;
        ushort4 o;
        o.x = Ls[n4 + 0][d]; o.y = Ls[n4 + 1][d];
        o.z = Ls[n4 + 2][d]; o.w = Ls[n4 + 3][d];
        *(ushort4*)&Vt[(size_t)(d0 + d) * 4096 + n0 + n4] = o;
    }
}

// prefix-causal row softmax: row r = r0+blockIdx.x over [0,r]; bf16 out,
// zero-padded to the 128-boundary (PV reads k < n0+128).
__global__ __launch_bounds__(TB)
void softmax_prefix(float* __restrict__ Sp, ushort* __restrict__ Pp, int r0)
{
    const int local = blockIdx.x;
    const int r = r0 + local;
    const int pe = ((r >> 7) << 7) + 128;
    float* p = Sp + (size_t)local * 4096;
    ushort* q = Pp + (size_t)local * 4096;
    const int t = threadIdx.x;
    const int wv = t >> 6, ln = t & 63;
    __shared__ float red[4];

    float lm = -INFINITY;
    for (int k4 = t * 4; k4 < pe; k4 += 1024) {
        float4 v = *(const float4*)&p[k4];
        lm = (k4 + 0 <= r) ? fmaxf(lm, v.x) : lm;
        lm = (k4 + 1 <= r) ? fmaxf(lm, v.y) : lm;
        lm = (k4 + 2 <= r) ? fmaxf(lm, v.z) : lm;
        lm = (k4 + 3 <= r) ? fmaxf(lm, v.w) : lm;
    }
    #pragma unroll
    for (int m = 1; m < 64; m <<= 1) lm = fmaxf(lm, __shfl_xor(lm, m, 64));
    if (ln == 0) red[wv] = lm;
    __syncthreads();
    const float mx = fmaxf(fmaxf(red[0], red[1]), fmaxf(red[2], red[3]));
    __syncthreads();

    float ls = 0.f;
    for (int k4 = t * 4; k4 < pe; k4 += 1024) {
        float4 v = *(const float4*)&p[k4];
        float4 e;
        e.x = (k4 + 0 <= r) ? __expf(v.x - mx) : 0.f;
        e.y = (k4 + 1 <= r) ? __expf(v.y - mx) : 0.f;
        e.z = (k4 + 2 <= r) ? __expf(v.z - mx) : 0.f;
        e.w = (k4 + 3 <= r) ? __expf(v.w - mx) : 0.f;
        ls += e.x + e.y + e.z + e.w;
        *(float4*)&p[k4] = e;
    }
    #pragma unroll
    for (int m = 1; m < 64; m <<= 1) ls += __shfl_xor(ls, m, 64);
    if (ln == 0) red[wv] = ls;
    __syncthreads();
    const float inv = 1.0f / (red[0] + red[1] + red[2] + red[3]);
    for (int k4 = t * 4; k4 < pe; k4 += 1024) {
        float4 e = *(const float4*)&p[k4];
        ushort4 o;
        o.x = f2bf(e.x * inv); o.y = f2bf(e.y * inv);
        o.z = f2bf(e.z * inv); o.w = f2bf(e.w * inv);
        *(ushort4*)&q[k4] = o;
    }
}

extern "C" void kernel_launch(void* const* d_in, const int* in_sizes, int n_in,
                              void* d_out, int out_size, void* d_ws, size_t ws_size,
                              hipStream_t stream)
{
    const float* x    = (const float*)d_in[0];   // [4,4096,1024]
    const float* Wqkv = (const float*)d_in[1];   // [3072,1024]
    const float* bqkv = (const float*)d_in[2];   // [3072]
    const float* Wo   = (const float*)d_in[3];   // [1024,1024]
    const float* bo   = (const float*)d_in[4];   // [1024]
    float* out = (float*)d_out;                  // [4,4096,1024] f32

    // ---- workspace: 209.8 MB total (same as R6/R7, proven to fit) ----
    ushort* Wq    = (ushort*)d_ws;                      // [3072][1024]      6.3 MB
    ushort* Wob   = Wq    + (size_t)3072 * 1024;        // [1024][1024]      2.1 MB
    ushort* qkvb  = Wob   + (size_t)1024 * 1024;        // [4096][3072]     25.2 MB
    ushort* Vtb   = qkvb  + (size_t)4096 * 3072;        // [1024][4096]      8.4 MB
    ushort* Tall  = Vtb   + (size_t)1024 * 4096;        // [4][1024][4096]  33.6 MB
    ushort* Pch   = Tall  + (size_t)4 * 1024 * 4096;    // [4096][4096]     33.6 MB
    float*  Sch   = (float*)(Pch + (size_t)4096 * 4096);// [4096][4096] f32 67.1 MB
    float*  Tpart = Sch + (size_t)4096 * 4096;          // [2][1024][4096]  33.6 MB
    ushort* xscr  = (ushort*)Tpart;                     // x_b bf16 scratch (8.4 MB,
                                                        //  dead before PV writes Tpart)
    dim3 blk(TB);

    conv_f32_bf16<<<256, blk, 0, stream>>>(Wqkv, Wq,  3072 * 1024 / 4);
    conv_f32_bf16<<<128, blk, 0, stream>>>(Wo,   Wob, 1024 * 1024 / 4);

    for (int b = 0; b < 4; b++) {
        const float* xb = x + (size_t)b * 4096 * 1024;

        // 0) x_b -> bf16 scratch (removes in-staging conversion latency)
        conv_f32_bf16<<<1024, blk, 0, stream>>>(xb, xscr, 4096 * 1024 / 4);

        // 1) qkv_b = x_b @ Wqkv^T + bqkv  (768 blocks, XCD-swizzled)
        gemm_bf16<128, 0, false, false, false, false, false, true>
            <<<dim3(24, 32), blk, 0, stream>>>(
            xscr, 1024, Wq, 1024, bqkv, qkvb, 3072, 1024, 1.f, 0);

        transposeV<<<dim3(64, 16), blk, 0, stream>>>(qkvb + 2048, 3072, Vtb);

        // 2) S = 0.125 * Q K^T  (BM=64: ~1100 blocks, longest rows first)
        gemm_bf16<64, 1, true, false, false, true, false, false>
            <<<dim3(32, 64), blk, 0, stream>>>(
            qkvb, 3072, qkvb + 1024, 3072, nullptr, Sch, 4096, 1024, 0.125f, 0);

        // 3) P = prefix-softmax(S) -> bf16 (zero-padded to 128-boundary)
        softmax_prefix<<<dim3(4096), blk, 0, stream>>>(Sch, Pch, 0);

        // 4) PV split-K x2, BM=64: 1024 blocks (4/CU)
        gemm_bf16<64, 1, false, true, true, false, true, false>
            <<<dim3(32, 16, 2), blk, 0, stream>>>(
            Vtb, 4096, Pch, 4096, nullptr, Tpart, 4096, 4096, 1.f, 0);

        // 4b) Tall_b = bf16(Tpart0 + Tpart1)
        reduce_pair_bf16<<<1024, blk, 0, stream>>>(
            Tpart, Tpart + (size_t)1024 * 4096,
            Tall + (size_t)b * 1024 * 4096, 1024 * 4096 / 4);
    }

    // 5) out = T @ Wo^T + bo  (1024 blocks, XCD-swizzled)
    gemm_bf16<128, 3, false, false, false, false, false, true>
        <<<dim3(8, 128), blk, 0, stream>>>(
        Tall, 1024, Wob, 1024, bo, out, 1024, 1024, 1.f, 0);
}